// Round 16
// baseline (151.996 us; speedup 1.0000x reference)
//
#include <hip/hip_runtime.h>

#define NUM_ENT 10000
#define NUM_REL 50
#define HID 64
#define NTRIP 500000
#define NSLOT 51            // 50 relations + residual slot
#define SSTR (NUM_ENT * HID)   // 640000: table slot stride, layout [slot][e][d]
#define ETILE 128
#define NETILE 79           // ceil(10000/128)
#define TRB (NSLOT * NETILE)   // 4029 transpose blocks
#define BSTR 192            // fixed bucket stride per tail (max tail cnt ~85)

typedef __attribute__((ext_vector_type(8))) short short8;
typedef __attribute__((ext_vector_type(4))) float f32x4;

// bf16 helpers (RNE)
static __device__ __forceinline__ unsigned short f2bf(float x) {
    unsigned u = __float_as_uint(x);
    return (unsigned short)((u + 0x7FFFu + ((u >> 16) & 1u)) >> 16);
}
static __device__ __forceinline__ float bf2f(unsigned short b) {
    return __uint_as_float((unsigned)b << 16);
}
static __device__ __forceinline__ short8 ld8(const unsigned short* p) {
    return *(const short8*)p;
}

// async global->LDS, 16 B per lane (global addr per-lane, LDS dest uniform+lane*16)
static __device__ __forceinline__ void gload_lds16(const float* g, float* l) {
    __builtin_amdgcn_global_load_lds(
        (const __attribute__((address_space(1))) unsigned*)g,
        (__attribute__((address_space(3))) unsigned*)l, 16, 0, 0);
}

// ============================================================
// fused prep: zero(bins) | diag0 | rel(diag1,outrel) | wconv | diag1-tail
// ============================================================

__global__ __launch_bounds__(256) void k_prep(const float* __restrict__ Wmr0,
                                              const float* __restrict__ Wpr0,
                                              const float* __restrict__ Wmr1,
                                              const float* __restrict__ Wpr1,
                                              const float* __restrict__ Wme1,
                                              const float* __restrict__ Wres1,
                                              int* __restrict__ bins,
                                              float* __restrict__ diag0,
                                              float* __restrict__ diag1,
                                              float* __restrict__ outrel,
                                              unsigned short* __restrict__ Wb) {
    int bid = blockIdx.x, tid = threadIdx.x;
    if (bid < 40) {                       // zero bins (10000)
        int i = bid * 256 + tid;
        if (i < NUM_ENT) bins[i] = 0;
        return;
    }
    bid -= 40;
    if (bid < 13) {                       // diag0 (NSLOT*64)
        int i = bid * 256 + tid;
        if (i < NSLOT * HID)
            diag0[i] = (i < NUM_REL * HID) ? Wmr0[(size_t)i * NUM_REL + (i >> 6)] : 0.f;
        return;
    }
    bid -= 13;
    if (bid < 13) {                       // rel: 4 relations per block
        __shared__ float wp[4][64];
        int sub = tid >> 6, d = tid & 63;
        int rr = bid * 4 + sub;
        wp[sub][d] = (rr < NUM_REL) ? Wpr0[d * NUM_REL + rr] : 0.f;
        __syncthreads();
        if (rr < NUM_REL) {
            float s1 = 0.f, s2 = 0.f;
            const float* wmr = Wmr1 + (size_t)(rr * HID + d) * HID;
            const float* wpr = Wpr1 + d * HID;
            for (int k = 0; k < HID; k++) {
                s1 += wp[sub][k] * wmr[k];
                s2 += wp[sub][k] * wpr[k];
            }
            diag1[rr * HID + d] = s1;
            outrel[rr * HID + d] = s2;
        }
        return;
    }
    bid -= 13;
    if (bid < 816) {                      // Wb: bf16(Wme1) | bf16(Wres1)
        int i = bid * 256 + tid;
        if (i < NSLOT * HID * HID)
            Wb[i] = f2bf(i < NUM_REL * HID * HID ? Wme1[i]
                                                 : Wres1[i - NUM_REL * HID * HID]);
        return;
    }
    // diag1 tail (slot 50) = 0
    if (tid < HID) diag1[NUM_REL * HID + tid] = 0.f;
}

// ============================================================
// fused build: transpose P (blocks 0..TRB-1) + one-pass rank+fill (rest).
// r16: read phase via 32x global_load_lds (16B/lane, 1KB/instr) into a
// linear raw fp32 tile — deep async queue, no VGPR serialization.
// Pack: LDS raw -> packed-uint utile (bijective XOR swizzle). Store: 1KB bursts.
// ============================================================

__global__ __launch_bounds__(256) void k_build(const float* __restrict__ Wme0,
                                               const float* __restrict__ Wres0,
                                               const float* __restrict__ diag0,
                                               unsigned short* __restrict__ P,
                                               const int* __restrict__ h,
                                               const int* __restrict__ r,
                                               const int* __restrict__ t,
                                               int* __restrict__ bins,
                                               unsigned* __restrict__ bucket2) {
    __shared__ __align__(16) float rawf[64][ETILE];       // 32 KB, [d][e] linear
    __shared__ __align__(16) unsigned utile[ETILE][32];   // 16 KB
    __shared__ float dg[64];
    int tid = threadIdx.x;

    if (blockIdx.x >= TRB) {
        // ---- one-pass rank + fill ----
        int i = ((int)blockIdx.x - TRB) * 256 + tid;
        if (i < NTRIP) {
            int tt = t[i];
            int lp = atomicAdd(&bins[tt], 1);
            if (lp < BSTR)
                bucket2[tt * BSTR + lp] =
                    (unsigned)r[i] * (unsigned)SSTR + (unsigned)h[i] * 64u;
        }
        return;
    }

    // ---- transpose ----
    int slot = blockIdx.x / NETILE;
    int ey = blockIdx.x - slot * NETILE;
    int e0 = ey * ETILE;
    const float* Wbase = (slot < NUM_REL)
        ? Wme0 + (size_t)(slot * HID) * NUM_ENT + e0
        : Wres0 + e0;
    unsigned short* Pslot = P + (size_t)slot * SSTR;

    if (e0 + ETILE <= NUM_ENT) {
        // ---- async stage: 8 global_load_lds per wave, all in flight ----
        int lane = tid & 63;
        int wv = tid >> 6;                 // wave 0..3
        int rsub = lane >> 5;              // 0/1: which row of the pair
        int ecol = (lane & 31) * 4;        // 16B-aligned e-offset
#pragma unroll
        for (int k = 0; k < 8; ++k) {
            int m = wv * 8 + k;            // row pair 0..31
            gload_lds16(Wbase + (size_t)(2 * m + rsub) * NUM_ENT + ecol,
                        &rawf[2 * m][0]);
        }
        if (tid < 64) dg[tid] = diag0[slot * HID + tid];
        __syncthreads();    // drains vmcnt (lds-load queue) + lgkm

        // ---- pack phase: LDS raw -> packed utile ----
        int dp = tid >> 5;            // 0..7
        int kk = tid & 31;            // lane e-group: e = 4*kk + j
        int x4 = kk * 4;
        int wf1 = kk & 7;             // (e>>2)&7, uniform over j
        int wf2 = kk >> 3;            // (e>>5)&3, uniform over j
#pragma unroll
        for (int it = 0; it < 4; ++it) {
            int d = it * 16 + dp * 2;
            int d2 = it * 8 + dp;
            float4 vA = *(const float4*)&rawf[d][x4];
            float4 vB = *(const float4*)&rawf[d + 1][x4];
            float dgA = dg[d], dgB = dg[d + 1];
            const float* a = (const float*)&vA;
            const float* b = (const float*)&vB;
            int col = (((d2 >> 2) ^ wf1) << 2) | ((d2 & 3) ^ wf2);
#pragma unroll
            for (int j = 0; j < 4; ++j) {
                utile[x4 + j][col] = (unsigned)f2bf(a[j] + dgA) |
                                     ((unsigned)f2bf(b[j] + dgB) << 16);
            }
        }
        __syncthreads();
        // ---- store phase: 4 ds_read_b128 + un-permute + 1KB-burst stores ----
#pragma unroll
        for (int it = 0; it < 4; ++it) {
            int idx = tid + it * 256;     // 0..1023
            int ee = idx >> 3;
            int q = idx & 7;              // logical 4-uint group = d 8q..8q+7
            int f1 = (ee >> 2) & 7;
            int f2 = (ee >> 5) & 3;
            uint4 u = *(const uint4*)&utile[ee][(q ^ f1) << 2];
            unsigned ua = u.x, ub = u.y, uc = u.z, ud = u.w;
            if (f2 & 1) { unsigned s0 = ua; ua = ub; ub = s0;
                          unsigned s1 = uc; uc = ud; ud = s1; }
            if (f2 & 2) { unsigned s0 = ua; ua = uc; uc = s0;
                          unsigned s1 = ub; ub = ud; ud = s1; }
            uint4 o = make_uint4(ua, ub, uc, ud);
            *(uint4*)&Pslot[(size_t)(e0 + ee) * 64 + q * 8] = o;
        }
    } else {
        if (tid < 64) dg[tid] = diag0[slot * HID + tid];
        __syncthreads();
        int rem = NUM_ENT - e0;
        for (int i = tid; i < rem * 64; i += 256) {
            int ee = i % rem;
            int dd = i / rem;
            float v = Wbase[(size_t)dd * NUM_ENT + ee] + dg[dd];
            Pslot[(size_t)(e0 + ee) * 64 + dd] = f2bf(v);
        }
    }
}

// ============================================================
// layer 1 table (MFMA): B[slot][e][d] = bf16(Abf[e,:].Wb[slot][d,:] + diag1[slot,d])
// ============================================================

__global__ __launch_bounds__(256) void k_gemmB(const unsigned short* __restrict__ Abf,
                                               const unsigned short* __restrict__ Wb,
                                               const float* __restrict__ diag1,
                                               unsigned short* __restrict__ B,
                                               int percut) {
    int e0 = blockIdx.x * 64;
    int rl0 = blockIdx.y * percut;
    int rl1 = rl0 + percut;
    if (rl1 > NSLOT) rl1 = NSLOT;
    int w = (int)threadIdx.x >> 6;
    int lane = (int)threadIdx.x & 63;
    int lrow = lane & 15;
    int hi = lane >> 4;
    int lk8 = hi * 8;
    int row = e0 + w * 16 + lrow;
    int rowc = row < NUM_ENT ? row : NUM_ENT - 1;
    short8 a0 = ld8(Abf + (size_t)rowc * HID + lk8);
    short8 a1 = ld8(Abf + (size_t)rowc * HID + 32 + lk8);

    for (int rl = rl0; rl < rl1; ++rl) {
        const unsigned short* wb = Wb + (size_t)rl * 4096;
        f32x4 acc[4] = {};
#pragma unroll
        for (int tt = 0; tt < 4; ++tt) {
            const unsigned short* wd = wb + (tt * 16 + lrow) * 64;
            short8 b0 = ld8(wd + lk8);
            short8 b1 = ld8(wd + 32 + lk8);
            acc[tt] = __builtin_amdgcn_mfma_f32_16x16x32_bf16(a0, b0, acc[tt], 0, 0, 0);
            acc[tt] = __builtin_amdgcn_mfma_f32_16x16x32_bf16(a1, b1, acc[tt], 0, 0, 0);
        }
        unsigned short* Bslot = B + (size_t)rl * SSTR;
#pragma unroll
        for (int tt = 0; tt < 4; ++tt) {
            float dgv = diag1[rl * HID + tt * 16 + lrow];
#pragma unroll
            for (int q = 0; q < 4; ++q) {
                int eo = e0 + w * 16 + hi * 4 + q;
                if (eo < NUM_ENT)
                    Bslot[(size_t)eo * 64 + tt * 16 + lrow] = f2bf(acc[tt][q] + dgv);
            }
        }
    }
}

// ============================================================
// tail-owned gather: v[e,:] = lrelu( sum_j table[off_j,:] + table[slot50][e,:] )
// fixed-stride buckets: entries at bucket2[e*BSTR .. e*BSTR+bins[e])
// ============================================================

__global__ __launch_bounds__(256) void k_scatter(const unsigned short* __restrict__ table,
                                                 const int* __restrict__ bins,
                                                 const unsigned* __restrict__ bucket2,
                                                 unsigned short* __restrict__ Abf,
                                                 float* __restrict__ outF,
                                                 int writeBf) {
    int e = __builtin_amdgcn_readfirstlane(blockIdx.x * 4 + (threadIdx.x >> 6));
    if (e >= NUM_ENT) return;
    int lane = threadIdx.x & 63;
    int oct = lane >> 3;     // which triplet row in the batch of 8
    int sl = lane & 7;       // d-slice: d = 8*sl .. 8*sl+7
    int cnt = bins[e];
    if (cnt > BSTR) cnt = BSTR;
    int j0 = e * BSTR, j1 = j0 + cnt;
    float acc[8] = {};
    float acc2[8] = {};
    int jj = j0;
    for (; jj + 16 <= j1; jj += 16) {
        unsigned o0 = bucket2[jj + oct];
        unsigned o1 = bucket2[jj + 8 + oct];
        short8 v0 = ld8(table + o0 + sl * 8);
        short8 v1 = ld8(table + o1 + sl * 8);
#pragma unroll
        for (int k = 0; k < 8; ++k) {
            acc[k]  += bf2f(((const unsigned short*)&v0)[k]);
            acc2[k] += bf2f(((const unsigned short*)&v1)[k]);
        }
    }
    if (jj + 8 <= j1) {
        unsigned o = bucket2[jj + oct];
        short8 v = ld8(table + o + sl * 8);
#pragma unroll
        for (int k = 0; k < 8; ++k) acc[k] += bf2f(((const unsigned short*)&v)[k]);
        jj += 8;
    }
    if (oct < j1 - jj) {
        unsigned o = bucket2[jj + oct];
        short8 v = ld8(table + o + sl * 8);
#pragma unroll
        for (int k = 0; k < 8; ++k) acc2[k] += bf2f(((const unsigned short*)&v)[k]);
    }
#pragma unroll
    for (int k = 0; k < 8; ++k) {
        acc[k] += acc2[k];
        acc[k] += __shfl_xor(acc[k], 8);
        acc[k] += __shfl_xor(acc[k], 16);
        acc[k] += __shfl_xor(acc[k], 32);
    }
    if (oct == 0) {
        short8 base = ld8(table + (size_t)(NSLOT - 1) * SSTR + (size_t)e * HID + sl * 8);
        float v[8];
#pragma unroll
        for (int k = 0; k < 8; ++k) {
            float x = acc[k] + bf2f(((const unsigned short*)&base)[k]);
            v[k] = (x >= 0.f) ? x : 0.01f * x;
        }
        if (writeBf) {
            unsigned short pk[8];
#pragma unroll
            for (int k = 0; k < 8; ++k) pk[k] = f2bf(v[k]);
            *(short8*)&Abf[(size_t)e * HID + sl * 8] = *(const short8*)pk;
        } else {
            *(float4*)&outF[(size_t)e * HID + sl * 8] = make_float4(v[0], v[1], v[2], v[3]);
            *(float4*)&outF[(size_t)e * HID + sl * 8 + 4] = make_float4(v[4], v[5], v[6], v[7]);
        }
    }
}

// ============================================================
// fallback path (round-1 atomic kernels) — used only if ws too small
// ============================================================

__global__ void k_rel(const float* __restrict__ Wpr0, const float* __restrict__ Wmr1,
                      const float* __restrict__ Wpr1, float* __restrict__ diag1,
                      float* __restrict__ outrel) {
    __shared__ float wp[HID];
    int rr = blockIdx.x, d = threadIdx.x;
    wp[d] = Wpr0[d * NUM_REL + rr];
    __syncthreads();
    float s1 = 0.0f, s2 = 0.0f;
    const float* wmr = Wmr1 + (size_t)(rr * HID + d) * HID;
    const float* wpr = Wpr1 + d * HID;
    for (int k = 0; k < HID; k++) { s1 += wp[k] * wmr[k]; s2 += wp[k] * wpr[k]; }
    diag1[rr * HID + d] = s1;
    outrel[rr * HID + d] = s2;
}

__global__ void k_init_u0(const float* __restrict__ Wres0, float* __restrict__ U0) {
    __shared__ float tile[64][65];
    int e0 = blockIdx.x * 64;
    for (int i = threadIdx.x; i < 64 * 64; i += 256) {
        int dd = i >> 6, xx = i & 63;
        if (e0 + xx < NUM_ENT) tile[xx][dd] = Wres0[dd * NUM_ENT + e0 + xx];
    }
    __syncthreads();
    for (int i = threadIdx.x; i < 64 * 64; i += 256) {
        int ee = i >> 6, dd = i & 63;
        if (e0 + ee < NUM_ENT) U0[(e0 + ee) * HID + dd] = tile[ee][dd];
    }
}

__global__ void k_hist(const int* __restrict__ r, int* __restrict__ hist) {
    __shared__ int lh[NUM_REL];
    int tid = threadIdx.x;
    if (tid < NUM_REL) lh[tid] = 0;
    __syncthreads();
    int i = blockIdx.x * blockDim.x + tid;
    if (i < NTRIP) atomicAdd(&lh[r[i]], 1);
    __syncthreads();
    if (tid < NUM_REL && lh[tid] > 0) atomicAdd(&hist[tid], lh[tid]);
}

__global__ void k_scan_small(const int* __restrict__ hist, int* __restrict__ off,
                             int* __restrict__ cur) {
    if (threadIdx.x == 0 && blockIdx.x == 0) {
        int s = 0;
        for (int i = 0; i < NUM_REL; i++) { off[i] = s; cur[i] = s; s += hist[i]; }
        off[NUM_REL] = s;
    }
}

__global__ void k_bucket(const int* __restrict__ h, const int* __restrict__ r,
                         const int* __restrict__ t, int* __restrict__ cur,
                         int2* __restrict__ bucket) {
    __shared__ int lcnt[NUM_REL];
    __shared__ int lbase[NUM_REL];
    int tid = threadIdx.x;
    if (tid < NUM_REL) lcnt[tid] = 0;
    __syncthreads();
    int i = blockIdx.x * blockDim.x + tid;
    int rr = -1, lpos = 0;
    if (i < NTRIP) { rr = r[i]; lpos = atomicAdd(&lcnt[rr], 1); }
    __syncthreads();
    if (tid < NUM_REL && lcnt[tid] > 0) lbase[tid] = atomicAdd(&cur[tid], lcnt[tid]);
    __syncthreads();
    if (i < NTRIP) bucket[lbase[rr] + lpos] = make_int2(h[i], t[i]);
}

__global__ void k_l0(const float* __restrict__ Wme0, const float* __restrict__ Wmr0,
                     const int* __restrict__ off, const int2* __restrict__ bucket,
                     float* __restrict__ U0) {
    __shared__ float row[NUM_ENT];
    int rr = blockIdx.x >> 6;
    int d  = blockIdx.x & 63;
    const float4* src4 = (const float4*)(Wme0 + (size_t)(rr * HID + d) * NUM_ENT);
    float4* row4 = (float4*)row;
    for (int i = threadIdx.x; i < NUM_ENT / 4; i += blockDim.x) row4[i] = src4[i];
    __syncthreads();
    float wd0 = Wmr0[(size_t)(rr * HID + d) * NUM_REL + rr];
    int b0 = off[rr], b1 = off[rr + 1];
    for (int i = b0 + threadIdx.x; i < b1; i += blockDim.x) {
        int2 ht = bucket[i];
        atomicAdd(&U0[(size_t)ht.y * HID + d], row[ht.x] + wd0);
    }
}

__global__ void k_lrelu(float* __restrict__ x, int n) {
    int i = blockIdx.x * blockDim.x + threadIdx.x;
    if (i < n) { float v = x[i]; x[i] = v >= 0.0f ? v : 0.01f * v; }
}

__global__ void k_init_u1(const float* __restrict__ A, const float* __restrict__ Wres1,
                          float* __restrict__ out) {
    __shared__ float W[HID][HID + 1];
    int tid = threadIdx.x;
    for (int i = tid; i < HID * HID; i += 256) W[i >> 6][i & 63] = Wres1[i];
    __syncthreads();
    int g = blockIdx.x * 256 + tid;
    int e = g >> 6, d = g & 63;
    if (e >= NUM_ENT) return;
    const float4* arow = (const float4*)(A + (size_t)e * HID);
    float acc = 0.0f;
#pragma unroll
    for (int k4 = 0; k4 < 16; k4++) {
        float4 a = arow[k4];
        acc = fmaf(a.x, W[d][k4 * 4 + 0], acc);
        acc = fmaf(a.y, W[d][k4 * 4 + 1], acc);
        acc = fmaf(a.z, W[d][k4 * 4 + 2], acc);
        acc = fmaf(a.w, W[d][k4 * 4 + 3], acc);
    }
    out[g] = acc;
}

#define L1_CHUNKS 16
__global__ void k_l1(const float* __restrict__ A, const float* __restrict__ Wme1,
                     const int* __restrict__ off, const int2* __restrict__ bucket,
                     const float* __restrict__ diag1, float* __restrict__ out) {
    int rr = blockIdx.x / L1_CHUNKS;
    int chunk = blockIdx.x % L1_CHUNKS;
    int b0 = off[rr], b1 = off[rr + 1];
    for (int i = b0 + chunk * 256 + (int)threadIdx.x; i < b1; i += L1_CHUNKS * 256) {
        int2 ht = bucket[i];
        const float4* arow = (const float4*)(A + (size_t)ht.x * HID);
        float4 a[16];
#pragma unroll
        for (int j = 0; j < 16; j++) a[j] = arow[j];
        float* op = out + (size_t)ht.y * HID;
#pragma unroll 4
        for (int d = 0; d < HID; d++) {
            const float4* m4 = (const float4*)(Wme1 + (size_t)(rr * HID + d) * HID);
            float acc = diag1[rr * HID + d];
#pragma unroll
            for (int k = 0; k < 16; k++) {
                float4 m = m4[k];
                acc = fmaf(a[k].x, m.x, acc);
                acc = fmaf(a[k].y, m.y, acc);
                acc = fmaf(a[k].z, m.z, acc);
                acc = fmaf(a[k].w, m.w, acc);
            }
            atomicAdd(op + d, acc);
        }
    }
}

// ============================================================
// launch
// ============================================================

static inline size_t align_up(size_t x, size_t a) { return (x + a - 1) & ~(a - 1); }

extern "C" void kernel_launch(void* const* d_in, const int* in_sizes, int n_in,
                              void* d_out, int out_size, void* d_ws, size_t ws_size,
                              hipStream_t stream) {
    const float* Wres0 = (const float*)d_in[0];
    const float* Wme0  = (const float*)d_in[1];
    const float* Wmr0  = (const float*)d_in[2];
    const float* Wpr0  = (const float*)d_in[3];
    const float* Wres1 = (const float*)d_in[4];
    const float* Wme1  = (const float*)d_in[5];
    const float* Wmr1  = (const float*)d_in[6];
    const float* Wpr1  = (const float*)d_in[7];
    const int* h = (const int*)d_in[8];
    const int* r = (const int*)d_in[9];
    const int* t = (const int*)d_in[10];
    float* out = (float*)d_out;  // [640000 ent | 3200 rel]

    char* ws = (char*)d_ws;
    const int nbt = (NTRIP + 255) / 256;       // 1954
    const int net = (NUM_ENT + 63) / 64;       // 157

    // workspace layout (fast path)
    size_t p = 0;
    size_t oTab  = p; p += align_up((size_t)NSLOT * SSTR * 2, 256);   // 65.28 MB
    size_t oB2   = p; p += align_up((size_t)NUM_ENT * BSTR * 4, 256); // 7.68 MB
    size_t oBins = p; p += align_up((size_t)NUM_ENT * 4, 256);
    size_t oAbf  = p; p += align_up((size_t)NUM_ENT * HID * 2, 256);
    size_t oD0   = p; p += align_up((size_t)NSLOT * HID * 4, 256);
    size_t oD1   = p; p += align_up((size_t)NSLOT * HID * 4, 256);
    size_t oWb   = p; p += align_up((size_t)NSLOT * HID * HID * 2, 256);
    size_t need = p;

    if (need <= ws_size) {
        unsigned short* Tab = (unsigned short*)(ws + oTab);   // P then B
        unsigned* bucket2   = (unsigned*)(ws + oB2);
        int*      bins      = (int*)(ws + oBins);
        unsigned short* Abf = (unsigned short*)(ws + oAbf);
        float*    diag0     = (float*)(ws + oD0);
        float*    diag1     = (float*)(ws + oD1);
        unsigned short* Wb  = (unsigned short*)(ws + oWb);
        const int nsplit = 6;
        const int percut = (NSLOT + nsplit - 1) / nsplit;     // 9

        // 1. fused prep (zero bins | diag0 | rel | Wb | diag1-tail)
        k_prep<<<883, 256, 0, stream>>>(Wmr0, Wpr0, Wmr1, Wpr1, Wme1, Wres1,
                                        bins, diag0, diag1, out + NUM_ENT * HID, Wb);
        // 2. fused transpose (async LDS staging) + one-pass rank&fill
        k_build<<<TRB + nbt, 256, 0, stream>>>(Wme0, Wres0, diag0, Tab,
                                               h, r, t, bins, bucket2);
        // 3. layer-0 gather -> Abf (bf16 A)
        k_scatter<<<(NUM_ENT + 3) / 4, 256, 0, stream>>>(
            Tab, bins, bucket2, Abf, out, 1);
        // 4. layer-1 table (MFMA)
        k_gemmB<<<dim3(net, nsplit), 256, 0, stream>>>(Abf, Wb, diag1, Tab, percut);
        // 5. layer-1 gather -> out
        k_scatter<<<(NUM_ENT + 3) / 4, 256, 0, stream>>>(
            Tab, bins, bucket2, Abf, out, 0);
        return;
    }

    // ---------- fallback: round-1 atomic path ----------
    {
        int2*  bucket = (int2*)ws;                    // 4,000,000 B
        float* U0     = (float*)(ws + 4000000);       // 2,560,000 B
        float* diag1  = (float*)(ws + 6560000);       // 12,800 B
        int*   hist   = (int*)(ws + 6572800);
        int*   off    = (int*)(ws + 6573056);
        int*   cur    = (int*)(ws + 6573312);

        hipMemsetAsync(hist, 0, NUM_REL * sizeof(int), stream);
        k_hist<<<nbt, 256, 0, stream>>>(r, hist);
        k_scan_small<<<1, 64, 0, stream>>>(hist, off, cur);
        k_bucket<<<nbt, 256, 0, stream>>>(h, r, t, cur, bucket);

        k_init_u0<<<net, 256, 0, stream>>>(Wres0, U0);
        k_l0<<<NUM_REL * HID, 256, 0, stream>>>(Wme0, Wmr0, off, bucket, U0);
        k_lrelu<<<(NUM_ENT * HID + 255) / 256, 256, 0, stream>>>(U0, NUM_ENT * HID);

        k_rel<<<NUM_REL, HID, 0, stream>>>(Wpr0, Wmr1, Wpr1, diag1, out + NUM_ENT * HID);
        k_init_u1<<<(NUM_ENT * HID) / 256, 256, 0, stream>>>(U0, Wres1, out);
        k_l1<<<NUM_REL * L1_CHUNKS, 256, 0, stream>>>(U0, Wme1, off, bucket, diag1, out);
        k_lrelu<<<(NUM_ENT * HID + 255) / 256, 256, 0, stream>>>(out, NUM_ENT * HID);
    }
}

// Round 17
// 136.841 us; speedup vs baseline: 1.1107x; 1.1107x over previous
//
#include <hip/hip_runtime.h>

#define NUM_ENT 10000
#define NUM_REL 50
#define HID 64
#define NTRIP 500000
#define NSLOT 51            // 50 relations + residual slot
#define SSTR (NUM_ENT * HID)   // 640000 elements: table slot stride [slot][e][d]
#define ETILE 128
#define NETILE 79           // ceil(10000/128)
#define TRB (NSLOT * NETILE)   // 4029 transpose blocks
#define BSTR 192            // fixed bucket stride per tail (max tail cnt ~85)

typedef __attribute__((ext_vector_type(8))) short short8;
typedef __attribute__((ext_vector_type(4))) float f32x4;

// bf16 helpers (RNE)
static __device__ __forceinline__ unsigned short f2bf(float x) {
    unsigned u = __float_as_uint(x);
    return (unsigned short)((u + 0x7FFFu + ((u >> 16) & 1u)) >> 16);
}
static __device__ __forceinline__ float bf2f(unsigned short b) {
    return __uint_as_float((unsigned)b << 16);
}
static __device__ __forceinline__ short8 ld8(const unsigned short* p) {
    return *(const short8*)p;
}

// fp8 e4m3 (OCP) manual encode/decode. Values here are small (|x| < 1).
static __device__ __forceinline__ unsigned f2fp8(float x) {
    unsigned u = __float_as_uint(x);
    unsigned s = (u >> 24) & 0x80u;
    float a = __uint_as_float(u & 0x7fffffffu);
    unsigned code;
    if (a >= 0.015625f) {  // normal (>= 2^-6)
        unsigned r = (u & 0x7fffffffu) + 0x7FFFFu + ((u >> 20) & 1u);  // RNE at bit20
        int e = (int)((r >> 23) & 0xff) - 127;
        unsigned m = (r >> 20) & 7u;
        if (e > 8) { e = 8; m = 6; }             // clamp to 448
        if (e == 8 && m == 7) m = 6;             // avoid NaN encoding
        code = ((unsigned)(e + 7) << 3) | m;
    } else {               // denormal: step 2^-9 (code 8 == 2^-6 seamlessly)
        code = (unsigned)__float2int_rn(a * 512.0f);
    }
    return code | s;
}
static __device__ __forceinline__ float fp8dec(unsigned c) {
    unsigned e = (c >> 3) & 15u;
    unsigned m = c & 7u;
    unsigned mm = m + (e ? 8u : 0u);
    unsigned eb = (e ? e : 1u) + 117u;           // biased exp of 2^(e-10)
    float f = (float)mm * __uint_as_float(eb << 23);
    return (c & 0x80u) ? -f : f;
}

// ============================================================
// fused prep: zero(bins) | diag0 | rel(diag1,outrel) | wconv | diag1-tail
// ============================================================

__global__ __launch_bounds__(256) void k_prep(const float* __restrict__ Wmr0,
                                              const float* __restrict__ Wpr0,
                                              const float* __restrict__ Wmr1,
                                              const float* __restrict__ Wpr1,
                                              const float* __restrict__ Wme1,
                                              const float* __restrict__ Wres1,
                                              int* __restrict__ bins,
                                              float* __restrict__ diag0,
                                              float* __restrict__ diag1,
                                              float* __restrict__ outrel,
                                              unsigned short* __restrict__ Wb) {
    int bid = blockIdx.x, tid = threadIdx.x;
    if (bid < 40) {                       // zero bins (10000)
        int i = bid * 256 + tid;
        if (i < NUM_ENT) bins[i] = 0;
        return;
    }
    bid -= 40;
    if (bid < 13) {                       // diag0 (NSLOT*64)
        int i = bid * 256 + tid;
        if (i < NSLOT * HID)
            diag0[i] = (i < NUM_REL * HID) ? Wmr0[(size_t)i * NUM_REL + (i >> 6)] : 0.f;
        return;
    }
    bid -= 13;
    if (bid < 13) {                       // rel: 4 relations per block
        __shared__ float wp[4][64];
        int sub = tid >> 6, d = tid & 63;
        int rr = bid * 4 + sub;
        wp[sub][d] = (rr < NUM_REL) ? Wpr0[d * NUM_REL + rr] : 0.f;
        __syncthreads();
        if (rr < NUM_REL) {
            float s1 = 0.f, s2 = 0.f;
            const float* wmr = Wmr1 + (size_t)(rr * HID + d) * HID;
            const float* wpr = Wpr1 + d * HID;
            for (int k = 0; k < HID; k++) {
                s1 += wp[sub][k] * wmr[k];
                s2 += wp[sub][k] * wpr[k];
            }
            diag1[rr * HID + d] = s1;
            outrel[rr * HID + d] = s2;
        }
        return;
    }
    bid -= 13;
    if (bid < 816) {                      // Wb: bf16(Wme1) | bf16(Wres1)
        int i = bid * 256 + tid;
        if (i < NSLOT * HID * HID)
            Wb[i] = f2bf(i < NUM_REL * HID * HID ? Wme1[i]
                                                 : Wres1[i - NUM_REL * HID * HID]);
        return;
    }
    // diag1 tail (slot 50) = 0
    if (tid < HID) diag1[NUM_REL * HID + tid] = 0.f;
}

// ============================================================
// fused build: transpose -> fp8 P table (blocks 0..TRB-1) + one-pass
// rank+fill (rest). P layout [slot][e][d], 64 B rows; 512 B burst stores.
// ============================================================

__global__ __launch_bounds__(256) void k_build(const float* __restrict__ Wme0,
                                               const float* __restrict__ Wres0,
                                               const float* __restrict__ diag0,
                                               unsigned char* __restrict__ P8,
                                               const int* __restrict__ h,
                                               const int* __restrict__ r,
                                               const int* __restrict__ t,
                                               int* __restrict__ bins,
                                               unsigned* __restrict__ bucket2) {
    __shared__ __align__(16) unsigned utile[ETILE][32];   // 16 KB (bf16 pairs)
    __shared__ float dg[64];
    int tid = threadIdx.x;

    if (blockIdx.x >= TRB) {
        // ---- one-pass rank + fill ----
        int i = ((int)blockIdx.x - TRB) * 256 + tid;
        if (i < NTRIP) {
            int tt = t[i];
            int lp = atomicAdd(&bins[tt], 1);
            if (lp < BSTR)
                bucket2[tt * BSTR + lp] =
                    (unsigned)r[i] * (unsigned)SSTR + (unsigned)h[i] * 64u;
        }
        return;
    }

    // ---- transpose ----
    int slot = blockIdx.x / NETILE;
    int ey = blockIdx.x - slot * NETILE;
    int e0 = ey * ETILE;
    const float* Wbase = (slot < NUM_REL)
        ? Wme0 + (size_t)(slot * HID) * NUM_ENT + e0
        : Wres0 + e0;
    unsigned char* Pslot = P8 + (size_t)slot * SSTR;

    if (e0 + ETILE <= NUM_ENT) {
        int dp = tid >> 5;            // 0..7
        int kk = tid & 31;            // lane e-group: e = 4*kk + j
        int x4 = kk * 4;
        int wf1 = kk & 7;
        int wf2 = kk >> 3;
        const float* p0 = Wbase + (size_t)(dp * 2 + 0) * NUM_ENT + x4;
        const float* p1 = Wbase + (size_t)(dp * 2 + 1) * NUM_ENT + x4;
        float4 vA0 = *(const float4*)(p0);
        float4 vB0 = *(const float4*)(p1);
        float4 vA1 = *(const float4*)(p0 + 16 * NUM_ENT);
        float4 vB1 = *(const float4*)(p1 + 16 * NUM_ENT);
        float4 vA2 = *(const float4*)(p0 + 32 * NUM_ENT);
        float4 vB2 = *(const float4*)(p1 + 32 * NUM_ENT);
        float4 vA3 = *(const float4*)(p0 + 48 * NUM_ENT);
        float4 vB3 = *(const float4*)(p1 + 48 * NUM_ENT);

        if (tid < 64) dg[tid] = diag0[slot * HID + tid];
        __syncthreads();

#define PACK_IT(IT, VA, VB)                                                     \
        {                                                                       \
            int d = IT * 16 + dp * 2;                                           \
            int d2 = IT * 8 + dp;                                               \
            float dgA = dg[d], dgB = dg[d + 1];                                 \
            const float* a = (const float*)&VA;                                 \
            const float* b = (const float*)&VB;                                 \
            int col = (((d2 >> 2) ^ wf1) << 2) | ((d2 & 3) ^ wf2);              \
            utile[x4 + 0][col] = (unsigned)f2bf(a[0] + dgA) |                   \
                                 ((unsigned)f2bf(b[0] + dgB) << 16);            \
            utile[x4 + 1][col] = (unsigned)f2bf(a[1] + dgA) |                   \
                                 ((unsigned)f2bf(b[1] + dgB) << 16);            \
            utile[x4 + 2][col] = (unsigned)f2bf(a[2] + dgA) |                   \
                                 ((unsigned)f2bf(b[2] + dgB) << 16);            \
            utile[x4 + 3][col] = (unsigned)f2bf(a[3] + dgA) |                   \
                                 ((unsigned)f2bf(b[3] + dgB) << 16);            \
        }
        PACK_IT(0, vA0, vB0)
        PACK_IT(1, vA1, vB1)
        PACK_IT(2, vA2, vB2)
        PACK_IT(3, vA3, vB3)
#undef PACK_IT
        __syncthreads();
        // ---- store: un-permute + bf16->fp8 + 512B-burst uint2 stores ----
#pragma unroll
        for (int it = 0; it < 4; ++it) {
            int idx = tid + it * 256;     // 0..1023
            int ee = idx >> 3;
            int q = idx & 7;              // d 8q..8q+7
            int f1 = (ee >> 2) & 7;
            int f2 = (ee >> 5) & 3;
            uint4 u = *(const uint4*)&utile[ee][(q ^ f1) << 2];
            unsigned ua = u.x, ub = u.y, uc = u.z, ud = u.w;
            if (f2 & 1) { unsigned s0 = ua; ua = ub; ub = s0;
                          unsigned s1 = uc; uc = ud; ud = s1; }
            if (f2 & 2) { unsigned s0 = ua; ua = uc; uc = s0;
                          unsigned s1 = ub; ub = ud; ud = s1; }
            unsigned lo = f2fp8(bf2f((unsigned short)ua))
                        | (f2fp8(bf2f((unsigned short)(ua >> 16))) << 8)
                        | (f2fp8(bf2f((unsigned short)ub)) << 16)
                        | (f2fp8(bf2f((unsigned short)(ub >> 16))) << 24);
            unsigned hi = f2fp8(bf2f((unsigned short)uc))
                        | (f2fp8(bf2f((unsigned short)(uc >> 16))) << 8)
                        | (f2fp8(bf2f((unsigned short)ud)) << 16)
                        | (f2fp8(bf2f((unsigned short)(ud >> 16))) << 24);
            *(uint2*)&Pslot[(size_t)(e0 + ee) * 64 + q * 8] = make_uint2(lo, hi);
        }
    } else {
        if (tid < 64) dg[tid] = diag0[slot * HID + tid];
        __syncthreads();
        int rem = NUM_ENT - e0;
        for (int i = tid; i < rem * 64; i += 256) {
            int ee = i % rem;
            int dd = i / rem;
            float v = Wbase[(size_t)dd * NUM_ENT + ee] + dg[dd];
            Pslot[(size_t)(e0 + ee) * 64 + dd] = (unsigned char)f2fp8(v);
        }
    }
}

// ============================================================
// layer 1 table (MFMA, 256-row e-tiles): B[slot][e][d] bf16
// ============================================================

__global__ __launch_bounds__(256) void k_gemmB(const unsigned short* __restrict__ Abf,
                                               const unsigned short* __restrict__ Wb,
                                               const float* __restrict__ diag1,
                                               unsigned short* __restrict__ B,
                                               int percut) {
    int e0 = blockIdx.x * 256;
    int rl0 = blockIdx.y * percut;
    int rl1 = rl0 + percut;
    if (rl1 > NSLOT) rl1 = NSLOT;
    int w = (int)threadIdx.x >> 6;
    int lane = (int)threadIdx.x & 63;
    int lrow = lane & 15;
    int hi = lane >> 4;
    int lk8 = hi * 8;
    int ew = e0 + w * 64;

    short8 am0[4], am1[4];
#pragma unroll
    for (int m = 0; m < 4; ++m) {
        int row = ew + m * 16 + lrow;
        int rowc = row < NUM_ENT ? row : NUM_ENT - 1;
        am0[m] = ld8(Abf + (size_t)rowc * HID + lk8);
        am1[m] = ld8(Abf + (size_t)rowc * HID + 32 + lk8);
    }

    for (int rl = rl0; rl < rl1; ++rl) {
        const unsigned short* wb = Wb + (size_t)rl * 4096;
        f32x4 acc[4][4] = {};
#pragma unroll
        for (int tt = 0; tt < 4; ++tt) {
            const unsigned short* wd = wb + (tt * 16 + lrow) * 64;
            short8 b0 = ld8(wd + lk8);
            short8 b1 = ld8(wd + 32 + lk8);
#pragma unroll
            for (int m = 0; m < 4; ++m) {
                acc[m][tt] = __builtin_amdgcn_mfma_f32_16x16x32_bf16(am0[m], b0, acc[m][tt], 0, 0, 0);
                acc[m][tt] = __builtin_amdgcn_mfma_f32_16x16x32_bf16(am1[m], b1, acc[m][tt], 0, 0, 0);
            }
        }
        unsigned short* Bslot = B + (size_t)rl * SSTR;
#pragma unroll
        for (int m = 0; m < 4; ++m) {
#pragma unroll
            for (int tt = 0; tt < 4; ++tt) {
                float dgv = diag1[rl * HID + tt * 16 + lrow];
#pragma unroll
                for (int q = 0; q < 4; ++q) {
                    int eo = ew + m * 16 + hi * 4 + q;
                    if (eo < NUM_ENT)
                        Bslot[(size_t)eo * 64 + tt * 16 + lrow] =
                            f2bf(acc[m][tt][q] + dgv);
                }
            }
        }
    }
}

// ============================================================
// tail-owned gather (templated on table dtype):
// v[e,:] = lrelu( sum_j table[off_j,:] + table[slot50][e,:] )
// ============================================================

template <int FP8>
__global__ __launch_bounds__(256) void k_scatter(const unsigned char* __restrict__ table,
                                                 const int* __restrict__ bins,
                                                 const unsigned* __restrict__ bucket2,
                                                 unsigned short* __restrict__ Abf,
                                                 float* __restrict__ outF,
                                                 int writeBf) {
    int e = __builtin_amdgcn_readfirstlane(blockIdx.x * 4 + (threadIdx.x >> 6));
    if (e >= NUM_ENT) return;
    int lane = threadIdx.x & 63;
    int oct = lane >> 3;     // triplet row within batch of 8
    int sl = lane & 7;       // d-slice: d = 8*sl .. 8*sl+7
    int cnt = bins[e];
    if (cnt > BSTR) cnt = BSTR;
    int j0 = e * BSTR, j1 = j0 + cnt;
    float acc[8] = {};
    float acc2[8] = {};
    int jj = j0;
#define GATHER8(O, ACC)                                                          \
    {                                                                            \
        if (FP8) {                                                               \
            uint2 v = *(const uint2*)(table + (size_t)(O) + sl * 8);             \
            ACC[0] += fp8dec(v.x & 255); ACC[1] += fp8dec((v.x >> 8) & 255);     \
            ACC[2] += fp8dec((v.x >> 16) & 255); ACC[3] += fp8dec(v.x >> 24);    \
            ACC[4] += fp8dec(v.y & 255); ACC[5] += fp8dec((v.y >> 8) & 255);     \
            ACC[6] += fp8dec((v.y >> 16) & 255); ACC[7] += fp8dec(v.y >> 24);    \
        } else {                                                                 \
            short8 v = ld8((const unsigned short*)(table + 2 * (size_t)(O)) + sl * 8); \
            for (int k = 0; k < 8; ++k)                                          \
                ACC[k] += bf2f(((const unsigned short*)&v)[k]);                  \
        }                                                                        \
    }
    for (; jj + 16 <= j1; jj += 16) {
        unsigned o0 = bucket2[jj + oct];
        unsigned o1 = bucket2[jj + 8 + oct];
        GATHER8(o0, acc)
        GATHER8(o1, acc2)
    }
    if (jj + 8 <= j1) {
        unsigned o = bucket2[jj + oct];
        GATHER8(o, acc)
        jj += 8;
    }
    if (oct < j1 - jj) {
        unsigned o = bucket2[jj + oct];
        GATHER8(o, acc2)
    }
#undef GATHER8
#pragma unroll
    for (int k = 0; k < 8; ++k) {
        acc[k] += acc2[k];
        acc[k] += __shfl_xor(acc[k], 8);
        acc[k] += __shfl_xor(acc[k], 16);
        acc[k] += __shfl_xor(acc[k], 32);
    }
    if (oct == 0) {
        size_t baseo = (size_t)(NSLOT - 1) * SSTR + (size_t)e * HID;
        float bse[8];
        if (FP8) {
            uint2 v = *(const uint2*)(table + baseo + sl * 8);
            bse[0] = fp8dec(v.x & 255); bse[1] = fp8dec((v.x >> 8) & 255);
            bse[2] = fp8dec((v.x >> 16) & 255); bse[3] = fp8dec(v.x >> 24);
            bse[4] = fp8dec(v.y & 255); bse[5] = fp8dec((v.y >> 8) & 255);
            bse[6] = fp8dec((v.y >> 16) & 255); bse[7] = fp8dec(v.y >> 24);
        } else {
            short8 v = ld8((const unsigned short*)(table + 2 * baseo) + sl * 8);
#pragma unroll
            for (int k = 0; k < 8; ++k) bse[k] = bf2f(((const unsigned short*)&v)[k]);
        }
        float v[8];
#pragma unroll
        for (int k = 0; k < 8; ++k) {
            float x = acc[k] + bse[k];
            v[k] = (x >= 0.f) ? x : 0.01f * x;
        }
        if (writeBf) {
            unsigned short pk[8];
#pragma unroll
            for (int k = 0; k < 8; ++k) pk[k] = f2bf(v[k]);
            *(short8*)&Abf[(size_t)e * HID + sl * 8] = *(const short8*)pk;
        } else {
            *(float4*)&outF[(size_t)e * HID + sl * 8] = make_float4(v[0], v[1], v[2], v[3]);
            *(float4*)&outF[(size_t)e * HID + sl * 8 + 4] = make_float4(v[4], v[5], v[6], v[7]);
        }
    }
}

// ============================================================
// fallback path (round-1 atomic kernels) — used only if ws too small
// ============================================================

__global__ void k_rel(const float* __restrict__ Wpr0, const float* __restrict__ Wmr1,
                      const float* __restrict__ Wpr1, float* __restrict__ diag1,
                      float* __restrict__ outrel) {
    __shared__ float wp[HID];
    int rr = blockIdx.x, d = threadIdx.x;
    wp[d] = Wpr0[d * NUM_REL + rr];
    __syncthreads();
    float s1 = 0.0f, s2 = 0.0f;
    const float* wmr = Wmr1 + (size_t)(rr * HID + d) * HID;
    const float* wpr = Wpr1 + d * HID;
    for (int k = 0; k < HID; k++) { s1 += wp[k] * wmr[k]; s2 += wp[k] * wpr[k]; }
    diag1[rr * HID + d] = s1;
    outrel[rr * HID + d] = s2;
}

__global__ void k_init_u0(const float* __restrict__ Wres0, float* __restrict__ U0) {
    __shared__ float tile[64][65];
    int e0 = blockIdx.x * 64;
    for (int i = threadIdx.x; i < 64 * 64; i += 256) {
        int dd = i >> 6, xx = i & 63;
        if (e0 + xx < NUM_ENT) tile[xx][dd] = Wres0[dd * NUM_ENT + e0 + xx];
    }
    __syncthreads();
    for (int i = threadIdx.x; i < 64 * 64; i += 256) {
        int ee = i >> 6, dd = i & 63;
        if (e0 + ee < NUM_ENT) U0[(e0 + ee) * HID + dd] = tile[ee][dd];
    }
}

__global__ void k_hist(const int* __restrict__ r, int* __restrict__ hist) {
    __shared__ int lh[NUM_REL];
    int tid = threadIdx.x;
    if (tid < NUM_REL) lh[tid] = 0;
    __syncthreads();
    int i = blockIdx.x * blockDim.x + tid;
    if (i < NTRIP) atomicAdd(&lh[r[i]], 1);
    __syncthreads();
    if (tid < NUM_REL && lh[tid] > 0) atomicAdd(&hist[tid], lh[tid]);
}

__global__ void k_scan_small(const int* __restrict__ hist, int* __restrict__ off,
                             int* __restrict__ cur) {
    if (threadIdx.x == 0 && blockIdx.x == 0) {
        int s = 0;
        for (int i = 0; i < NUM_REL; i++) { off[i] = s; cur[i] = s; s += hist[i]; }
        off[NUM_REL] = s;
    }
}

__global__ void k_bucket(const int* __restrict__ h, const int* __restrict__ r,
                         const int* __restrict__ t, int* __restrict__ cur,
                         int2* __restrict__ bucket) {
    __shared__ int lcnt[NUM_REL];
    __shared__ int lbase[NUM_REL];
    int tid = threadIdx.x;
    if (tid < NUM_REL) lcnt[tid] = 0;
    __syncthreads();
    int i = blockIdx.x * blockDim.x + tid;
    int rr = -1, lpos = 0;
    if (i < NTRIP) { rr = r[i]; lpos = atomicAdd(&lcnt[rr], 1); }
    __syncthreads();
    if (tid < NUM_REL && lcnt[tid] > 0) lbase[tid] = atomicAdd(&cur[tid], lcnt[tid]);
    __syncthreads();
    if (i < NTRIP) bucket[lbase[rr] + lpos] = make_int2(h[i], t[i]);
}

__global__ void k_l0(const float* __restrict__ Wme0, const float* __restrict__ Wmr0,
                     const int* __restrict__ off, const int2* __restrict__ bucket,
                     float* __restrict__ U0) {
    __shared__ float row[NUM_ENT];
    int rr = blockIdx.x >> 6;
    int d  = blockIdx.x & 63;
    const float4* src4 = (const float4*)(Wme0 + (size_t)(rr * HID + d) * NUM_ENT);
    float4* row4 = (float4*)row;
    for (int i = threadIdx.x; i < NUM_ENT / 4; i += blockDim.x) row4[i] = src4[i];
    __syncthreads();
    float wd0 = Wmr0[(size_t)(rr * HID + d) * NUM_REL + rr];
    int b0 = off[rr], b1 = off[rr + 1];
    for (int i = b0 + threadIdx.x; i < b1; i += blockDim.x) {
        int2 ht = bucket[i];
        atomicAdd(&U0[(size_t)ht.y * HID + d], row[ht.x] + wd0);
    }
}

__global__ void k_lrelu(float* __restrict__ x, int n) {
    int i = blockIdx.x * blockDim.x + threadIdx.x;
    if (i < n) { float v = x[i]; x[i] = v >= 0.0f ? v : 0.01f * v; }
}

__global__ void k_init_u1(const float* __restrict__ A, const float* __restrict__ Wres1,
                          float* __restrict__ out) {
    __shared__ float W[HID][HID + 1];
    int tid = threadIdx.x;
    for (int i = tid; i < HID * HID; i += 256) W[i >> 6][i & 63] = Wres1[i];
    __syncthreads();
    int g = blockIdx.x * 256 + tid;
    int e = g >> 6, d = g & 63;
    if (e >= NUM_ENT) return;
    const float4* arow = (const float4*)(A + (size_t)e * HID);
    float acc = 0.0f;
#pragma unroll
    for (int k4 = 0; k4 < 16; k4++) {
        float4 a = arow[k4];
        acc = fmaf(a.x, W[d][k4 * 4 + 0], acc);
        acc = fmaf(a.y, W[d][k4 * 4 + 1], acc);
        acc = fmaf(a.z, W[d][k4 * 4 + 2], acc);
        acc = fmaf(a.w, W[d][k4 * 4 + 3], acc);
    }
    out[g] = acc;
}

#define L1_CHUNKS 16
__global__ void k_l1(const float* __restrict__ A, const float* __restrict__ Wme1,
                     const int* __restrict__ off, const int2* __restrict__ bucket,
                     const float* __restrict__ diag1, float* __restrict__ out) {
    int rr = blockIdx.x / L1_CHUNKS;
    int chunk = blockIdx.x % L1_CHUNKS;
    int b0 = off[rr], b1 = off[rr + 1];
    for (int i = b0 + chunk * 256 + (int)threadIdx.x; i < b1; i += L1_CHUNKS * 256) {
        int2 ht = bucket[i];
        const float4* arow = (const float4*)(A + (size_t)ht.x * HID);
        float4 a[16];
#pragma unroll
        for (int j = 0; j < 16; j++) a[j] = arow[j];
        float* op = out + (size_t)ht.y * HID;
#pragma unroll 4
        for (int d = 0; d < HID; d++) {
            const float4* m4 = (const float4*)(Wme1 + (size_t)(rr * HID + d) * HID);
            float acc = diag1[rr * HID + d];
#pragma unroll
            for (int k = 0; k < 16; k++) {
                float4 m = m4[k];
                acc = fmaf(a[k].x, m.x, acc);
                acc = fmaf(a[k].y, m.y, acc);
                acc = fmaf(a[k].z, m.z, acc);
                acc = fmaf(a[k].w, m.w, acc);
            }
            atomicAdd(op + d, acc);
        }
    }
}

// ============================================================
// launch
// ============================================================

static inline size_t align_up(size_t x, size_t a) { return (x + a - 1) & ~(a - 1); }

extern "C" void kernel_launch(void* const* d_in, const int* in_sizes, int n_in,
                              void* d_out, int out_size, void* d_ws, size_t ws_size,
                              hipStream_t stream) {
    const float* Wres0 = (const float*)d_in[0];
    const float* Wme0  = (const float*)d_in[1];
    const float* Wmr0  = (const float*)d_in[2];
    const float* Wpr0  = (const float*)d_in[3];
    const float* Wres1 = (const float*)d_in[4];
    const float* Wme1  = (const float*)d_in[5];
    const float* Wmr1  = (const float*)d_in[6];
    const float* Wpr1  = (const float*)d_in[7];
    const int* h = (const int*)d_in[8];
    const int* r = (const int*)d_in[9];
    const int* t = (const int*)d_in[10];
    float* out = (float*)d_out;  // [640000 ent | 3200 rel]

    char* ws = (char*)d_ws;
    const int nbt = (NTRIP + 255) / 256;       // 1954

    // workspace layout (fast path); Tab shared: fp8 P then bf16 B
    size_t p = 0;
    size_t oTab  = p; p += align_up((size_t)NSLOT * SSTR * 2, 256);   // 65.28 MB
    size_t oB2   = p; p += align_up((size_t)NUM_ENT * BSTR * 4, 256); // 7.68 MB
    size_t oBins = p; p += align_up((size_t)NUM_ENT * 4, 256);
    size_t oAbf  = p; p += align_up((size_t)NUM_ENT * HID * 2, 256);
    size_t oD0   = p; p += align_up((size_t)NSLOT * HID * 4, 256);
    size_t oD1   = p; p += align_up((size_t)NSLOT * HID * 4, 256);
    size_t oWb   = p; p += align_up((size_t)NSLOT * HID * HID * 2, 256);
    size_t need = p;

    if (need <= ws_size) {
        unsigned char*  Tab8 = (unsigned char*)(ws + oTab);   // P (fp8) then B (bf16)
        unsigned short* TabH = (unsigned short*)(ws + oTab);
        unsigned* bucket2   = (unsigned*)(ws + oB2);
        int*      bins      = (int*)(ws + oBins);
        unsigned short* Abf = (unsigned short*)(ws + oAbf);
        float*    diag0     = (float*)(ws + oD0);
        float*    diag1     = (float*)(ws + oD1);
        unsigned short* Wb  = (unsigned short*)(ws + oWb);
        const int netile256 = (NUM_ENT + 255) / 256;          // 40
        const int nsplit = 13;
        const int percut = (NSLOT + nsplit - 1) / nsplit;     // 4

        // 1. fused prep (zero bins | diag0 | rel | Wb | diag1-tail)
        k_prep<<<883, 256, 0, stream>>>(Wmr0, Wpr0, Wmr1, Wpr1, Wme1, Wres1,
                                        bins, diag0, diag1, out + NUM_ENT * HID, Wb);
        // 2. fused transpose -> fp8 P + one-pass rank&fill
        k_build<<<TRB + nbt, 256, 0, stream>>>(Wme0, Wres0, diag0, Tab8,
                                               h, r, t, bins, bucket2);
        // 3. layer-0 gather (fp8) -> Abf (bf16 A)
        k_scatter<1><<<(NUM_ENT + 3) / 4, 256, 0, stream>>>(
            Tab8, bins, bucket2, Abf, out, 1);
        // 4. layer-1 table (MFMA, 256-row tiles) -> bf16 B (overwrites P)
        k_gemmB<<<dim3(netile256, nsplit), 256, 0, stream>>>(Abf, Wb, diag1, TabH,
                                                             percut);
        // 5. layer-1 gather (bf16) -> out
        k_scatter<0><<<(NUM_ENT + 3) / 4, 256, 0, stream>>>(
            Tab8, bins, bucket2, Abf, out, 0);
        return;
    }

    // ---------- fallback: round-1 atomic path ----------
    {
        const int net = (NUM_ENT + 63) / 64;
        int2*  bucket = (int2*)ws;                    // 4,000,000 B
        float* U0     = (float*)(ws + 4000000);       // 2,560,000 B
        float* diag1  = (float*)(ws + 6560000);       // 12,800 B
        int*   hist   = (int*)(ws + 6572800);
        int*   off    = (int*)(ws + 6573056);
        int*   cur    = (int*)(ws + 6573312);

        hipMemsetAsync(hist, 0, NUM_REL * sizeof(int), stream);
        k_hist<<<nbt, 256, 0, stream>>>(r, hist);
        k_scan_small<<<1, 64, 0, stream>>>(hist, off, cur);
        k_bucket<<<nbt, 256, 0, stream>>>(h, r, t, cur, bucket);

        k_init_u0<<<net, 256, 0, stream>>>(Wres0, U0);
        k_l0<<<NUM_REL * HID, 256, 0, stream>>>(Wme0, Wmr0, off, bucket, U0);
        k_lrelu<<<(NUM_ENT * HID + 255) / 256, 256, 0, stream>>>(U0, NUM_ENT * HID);

        k_rel<<<NUM_REL, HID, 0, stream>>>(Wpr0, Wmr1, Wpr1, diag1, out + NUM_ENT * HID);
        k_init_u1<<<(NUM_ENT * HID) / 256, 256, 0, stream>>>(U0, Wres1, out);
        k_l1<<<NUM_REL * L1_CHUNKS, 256, 0, stream>>>(U0, Wme1, off, bucket, diag1, out);
        k_lrelu<<<(NUM_ENT * HID + 255) / 256, 256, 0, stream>>>(out, NUM_ENT * HID);
    }
}

// Round 18
// 135.673 us; speedup vs baseline: 1.1203x; 1.0086x over previous
//
#include <hip/hip_runtime.h>

#define NUM_ENT 10000
#define NUM_REL 50
#define HID 64
#define NTRIP 500000
#define NSLOT 51            // 50 relations + residual slot
#define SSTR (NUM_ENT * HID)   // 640000 elements: table slot stride [slot][e][d]
#define ETILE 128
#define NETILE 79           // ceil(10000/128)
#define TRB (NSLOT * NETILE)   // 4029 transpose blocks
#define BSTR 192            // fixed bucket stride per tail (max tail cnt ~85)

typedef __attribute__((ext_vector_type(8))) short short8;
typedef __attribute__((ext_vector_type(4))) float f32x4;

// bf16 helpers (RNE)
static __device__ __forceinline__ unsigned short f2bf(float x) {
    unsigned u = __float_as_uint(x);
    return (unsigned short)((u + 0x7FFFu + ((u >> 16) & 1u)) >> 16);
}
static __device__ __forceinline__ float bf2f(unsigned short b) {
    return __uint_as_float((unsigned)b << 16);
}
static __device__ __forceinline__ short8 ld8(const unsigned short* p) {
    return *(const short8*)p;
}

// fp8 e4m3 (OCP) manual encode/decode. Values here are small (|x| < 1).
static __device__ __forceinline__ unsigned f2fp8(float x) {
    unsigned u = __float_as_uint(x);
    unsigned s = (u >> 24) & 0x80u;
    float a = __uint_as_float(u & 0x7fffffffu);
    unsigned code;
    if (a >= 0.015625f) {  // normal (>= 2^-6)
        unsigned r = (u & 0x7fffffffu) + 0x7FFFFu + ((u >> 20) & 1u);  // RNE at bit20
        int e = (int)((r >> 23) & 0xff) - 127;
        unsigned m = (r >> 20) & 7u;
        if (e > 8) { e = 8; m = 6; }             // clamp to 448
        if (e == 8 && m == 7) m = 6;             // avoid NaN encoding
        code = ((unsigned)(e + 7) << 3) | m;
    } else {               // denormal: step 2^-9 (code 8 == 2^-6 seamlessly)
        code = (unsigned)__float2int_rn(a * 512.0f);
    }
    return code | s;
}
static __device__ __forceinline__ float fp8dec(unsigned c) {
    unsigned e = (c >> 3) & 15u;
    unsigned m = c & 7u;
    unsigned mm = m + (e ? 8u : 0u);
    unsigned eb = (e ? e : 1u) + 117u;           // biased exp of 2^(e-10)
    float f = (float)mm * __uint_as_float(eb << 23);
    return (c & 0x80u) ? -f : f;
}

// ============================================================
// fused prep: zero(bins) | diag0 | rel(diag1,outrel) | wconv | diag1-tail
// ============================================================

__global__ __launch_bounds__(256) void k_prep(const float* __restrict__ Wmr0,
                                              const float* __restrict__ Wpr0,
                                              const float* __restrict__ Wmr1,
                                              const float* __restrict__ Wpr1,
                                              const float* __restrict__ Wme1,
                                              const float* __restrict__ Wres1,
                                              int* __restrict__ bins,
                                              float* __restrict__ diag0,
                                              float* __restrict__ diag1,
                                              float* __restrict__ outrel,
                                              unsigned short* __restrict__ Wb) {
    int bid = blockIdx.x, tid = threadIdx.x;
    if (bid < 40) {                       // zero bins (10000)
        int i = bid * 256 + tid;
        if (i < NUM_ENT) bins[i] = 0;
        return;
    }
    bid -= 40;
    if (bid < 13) {                       // diag0 (NSLOT*64)
        int i = bid * 256 + tid;
        if (i < NSLOT * HID)
            diag0[i] = (i < NUM_REL * HID) ? Wmr0[(size_t)i * NUM_REL + (i >> 6)] : 0.f;
        return;
    }
    bid -= 13;
    if (bid < 13) {                       // rel: 4 relations per block
        __shared__ float wp[4][64];
        int sub = tid >> 6, d = tid & 63;
        int rr = bid * 4 + sub;
        wp[sub][d] = (rr < NUM_REL) ? Wpr0[d * NUM_REL + rr] : 0.f;
        __syncthreads();
        if (rr < NUM_REL) {
            float s1 = 0.f, s2 = 0.f;
            const float* wmr = Wmr1 + (size_t)(rr * HID + d) * HID;
            const float* wpr = Wpr1 + d * HID;
            for (int k = 0; k < HID; k++) {
                s1 += wp[sub][k] * wmr[k];
                s2 += wp[sub][k] * wpr[k];
            }
            diag1[rr * HID + d] = s1;
            outrel[rr * HID + d] = s2;
        }
        return;
    }
    bid -= 13;
    if (bid < 816) {                      // Wb: bf16(Wme1) | bf16(Wres1)
        int i = bid * 256 + tid;
        if (i < NSLOT * HID * HID)
            Wb[i] = f2bf(i < NUM_REL * HID * HID ? Wme1[i]
                                                 : Wres1[i - NUM_REL * HID * HID]);
        return;
    }
    // diag1 tail (slot 50) = 0
    if (tid < HID) diag1[NUM_REL * HID + tid] = 0.f;
}

// ============================================================
// fused build: transpose -> fp8 P table (blocks 0..TRB-1) + one-pass
// rank+fill (rest). P layout [slot][e][d], 64 B rows; 512 B burst stores.
// ============================================================

__global__ __launch_bounds__(256) void k_build(const float* __restrict__ Wme0,
                                               const float* __restrict__ Wres0,
                                               const float* __restrict__ diag0,
                                               unsigned char* __restrict__ P8,
                                               const int* __restrict__ h,
                                               const int* __restrict__ r,
                                               const int* __restrict__ t,
                                               int* __restrict__ bins,
                                               unsigned* __restrict__ bucket2) {
    __shared__ __align__(16) unsigned utile[ETILE][32];   // 16 KB (bf16 pairs)
    __shared__ float dg[64];
    int tid = threadIdx.x;

    if (blockIdx.x >= TRB) {
        // ---- one-pass rank + fill ----
        int i = ((int)blockIdx.x - TRB) * 256 + tid;
        if (i < NTRIP) {
            int tt = t[i];
            int lp = atomicAdd(&bins[tt], 1);
            if (lp < BSTR)
                bucket2[tt * BSTR + lp] =
                    (unsigned)r[i] * (unsigned)SSTR + (unsigned)h[i] * 64u;
        }
        return;
    }

    // ---- transpose ----
    int slot = blockIdx.x / NETILE;
    int ey = blockIdx.x - slot * NETILE;
    int e0 = ey * ETILE;
    const float* Wbase = (slot < NUM_REL)
        ? Wme0 + (size_t)(slot * HID) * NUM_ENT + e0
        : Wres0 + e0;
    unsigned char* Pslot = P8 + (size_t)slot * SSTR;

    if (e0 + ETILE <= NUM_ENT) {
        int dp = tid >> 5;            // 0..7
        int kk = tid & 31;            // lane e-group: e = 4*kk + j
        int x4 = kk * 4;
        int wf1 = kk & 7;
        int wf2 = kk >> 3;
        const float* p0 = Wbase + (size_t)(dp * 2 + 0) * NUM_ENT + x4;
        const float* p1 = Wbase + (size_t)(dp * 2 + 1) * NUM_ENT + x4;
        float4 vA0 = *(const float4*)(p0);
        float4 vB0 = *(const float4*)(p1);
        float4 vA1 = *(const float4*)(p0 + 16 * NUM_ENT);
        float4 vB1 = *(const float4*)(p1 + 16 * NUM_ENT);
        float4 vA2 = *(const float4*)(p0 + 32 * NUM_ENT);
        float4 vB2 = *(const float4*)(p1 + 32 * NUM_ENT);
        float4 vA3 = *(const float4*)(p0 + 48 * NUM_ENT);
        float4 vB3 = *(const float4*)(p1 + 48 * NUM_ENT);

        if (tid < 64) dg[tid] = diag0[slot * HID + tid];
        __syncthreads();

#define PACK_IT(IT, VA, VB)                                                     \
        {                                                                       \
            int d = IT * 16 + dp * 2;                                           \
            int d2 = IT * 8 + dp;                                               \
            float dgA = dg[d], dgB = dg[d + 1];                                 \
            const float* a = (const float*)&VA;                                 \
            const float* b = (const float*)&VB;                                 \
            int col = (((d2 >> 2) ^ wf1) << 2) | ((d2 & 3) ^ wf2);              \
            utile[x4 + 0][col] = (unsigned)f2bf(a[0] + dgA) |                   \
                                 ((unsigned)f2bf(b[0] + dgB) << 16);            \
            utile[x4 + 1][col] = (unsigned)f2bf(a[1] + dgA) |                   \
                                 ((unsigned)f2bf(b[1] + dgB) << 16);            \
            utile[x4 + 2][col] = (unsigned)f2bf(a[2] + dgA) |                   \
                                 ((unsigned)f2bf(b[2] + dgB) << 16);            \
            utile[x4 + 3][col] = (unsigned)f2bf(a[3] + dgA) |                   \
                                 ((unsigned)f2bf(b[3] + dgB) << 16);            \
        }
        PACK_IT(0, vA0, vB0)
        PACK_IT(1, vA1, vB1)
        PACK_IT(2, vA2, vB2)
        PACK_IT(3, vA3, vB3)
#undef PACK_IT
        __syncthreads();
        // ---- store: un-permute + bf16->fp8 + 512B-burst uint2 stores ----
#pragma unroll
        for (int it = 0; it < 4; ++it) {
            int idx = tid + it * 256;     // 0..1023
            int ee = idx >> 3;
            int q = idx & 7;              // d 8q..8q+7
            int f1 = (ee >> 2) & 7;
            int f2 = (ee >> 5) & 3;
            uint4 u = *(const uint4*)&utile[ee][(q ^ f1) << 2];
            unsigned ua = u.x, ub = u.y, uc = u.z, ud = u.w;
            if (f2 & 1) { unsigned s0 = ua; ua = ub; ub = s0;
                          unsigned s1 = uc; uc = ud; ud = s1; }
            if (f2 & 2) { unsigned s0 = ua; ua = uc; uc = s0;
                          unsigned s1 = ub; ub = ud; ud = s1; }
            unsigned lo = f2fp8(bf2f((unsigned short)ua))
                        | (f2fp8(bf2f((unsigned short)(ua >> 16))) << 8)
                        | (f2fp8(bf2f((unsigned short)ub)) << 16)
                        | (f2fp8(bf2f((unsigned short)(ub >> 16))) << 24);
            unsigned hi = f2fp8(bf2f((unsigned short)uc))
                        | (f2fp8(bf2f((unsigned short)(uc >> 16))) << 8)
                        | (f2fp8(bf2f((unsigned short)ud)) << 16)
                        | (f2fp8(bf2f((unsigned short)(ud >> 16))) << 24);
            *(uint2*)&Pslot[(size_t)(e0 + ee) * 64 + q * 8] = make_uint2(lo, hi);
        }
    } else {
        if (tid < 64) dg[tid] = diag0[slot * HID + tid];
        __syncthreads();
        int rem = NUM_ENT - e0;
        for (int i = tid; i < rem * 64; i += 256) {
            int ee = i % rem;
            int dd = i / rem;
            float v = Wbase[(size_t)dd * NUM_ENT + ee] + dg[dd];
            Pslot[(size_t)(e0 + ee) * 64 + dd] = (unsigned char)f2fp8(v);
        }
    }
}

// ============================================================
// layer 1 table (MFMA, 256-row e-tiles): B[slot][e][d] bf16
// ============================================================

__global__ __launch_bounds__(256) void k_gemmB(const unsigned short* __restrict__ Abf,
                                               const unsigned short* __restrict__ Wb,
                                               const float* __restrict__ diag1,
                                               unsigned short* __restrict__ B,
                                               int percut) {
    int e0 = blockIdx.x * 256;
    int rl0 = blockIdx.y * percut;
    int rl1 = rl0 + percut;
    if (rl1 > NSLOT) rl1 = NSLOT;
    int w = (int)threadIdx.x >> 6;
    int lane = (int)threadIdx.x & 63;
    int lrow = lane & 15;
    int hi = lane >> 4;
    int lk8 = hi * 8;
    int ew = e0 + w * 64;

    short8 am0[4], am1[4];
#pragma unroll
    for (int m = 0; m < 4; ++m) {
        int row = ew + m * 16 + lrow;
        int rowc = row < NUM_ENT ? row : NUM_ENT - 1;
        am0[m] = ld8(Abf + (size_t)rowc * HID + lk8);
        am1[m] = ld8(Abf + (size_t)rowc * HID + 32 + lk8);
    }

    for (int rl = rl0; rl < rl1; ++rl) {
        const unsigned short* wb = Wb + (size_t)rl * 4096;
        f32x4 acc[4][4] = {};
#pragma unroll
        for (int tt = 0; tt < 4; ++tt) {
            const unsigned short* wd = wb + (tt * 16 + lrow) * 64;
            short8 b0 = ld8(wd + lk8);
            short8 b1 = ld8(wd + 32 + lk8);
#pragma unroll
            for (int m = 0; m < 4; ++m) {
                acc[m][tt] = __builtin_amdgcn_mfma_f32_16x16x32_bf16(am0[m], b0, acc[m][tt], 0, 0, 0);
                acc[m][tt] = __builtin_amdgcn_mfma_f32_16x16x32_bf16(am1[m], b1, acc[m][tt], 0, 0, 0);
            }
        }
        unsigned short* Bslot = B + (size_t)rl * SSTR;
#pragma unroll
        for (int m = 0; m < 4; ++m) {
#pragma unroll
            for (int tt = 0; tt < 4; ++tt) {
                float dgv = diag1[rl * HID + tt * 16 + lrow];
#pragma unroll
                for (int q = 0; q < 4; ++q) {
                    int eo = ew + m * 16 + hi * 4 + q;
                    if (eo < NUM_ENT)
                        Bslot[(size_t)eo * 64 + tt * 16 + lrow] =
                            f2bf(acc[m][tt][q] + dgv);
                }
            }
        }
    }
}

// ============================================================
// tail-owned gather (templated on table dtype):
// v[e,:] = lrelu( sum_j table[off_j,:] + table[slot50][e,:] )
// ============================================================

template <int FP8>
__global__ __launch_bounds__(256) void k_scatter(const unsigned char* __restrict__ table,
                                                 const int* __restrict__ bins,
                                                 const unsigned* __restrict__ bucket2,
                                                 unsigned short* __restrict__ Abf,
                                                 float* __restrict__ outF,
                                                 int writeBf) {
    int e = __builtin_amdgcn_readfirstlane(blockIdx.x * 4 + (threadIdx.x >> 6));
    if (e >= NUM_ENT) return;
    int lane = threadIdx.x & 63;
    int oct = lane >> 3;     // triplet row within batch of 8
    int sl = lane & 7;       // d-slice: d = 8*sl .. 8*sl+7
    int cnt = bins[e];
    if (cnt > BSTR) cnt = BSTR;
    int j0 = e * BSTR, j1 = j0 + cnt;
    float acc[8] = {};
    float acc2[8] = {};
    int jj = j0;
#define GATHER8(O, ACC)                                                          \
    {                                                                            \
        if (FP8) {                                                               \
            uint2 v = *(const uint2*)(table + (size_t)(O) + sl * 8);             \
            ACC[0] += fp8dec(v.x & 255); ACC[1] += fp8dec((v.x >> 8) & 255);     \
            ACC[2] += fp8dec((v.x >> 16) & 255); ACC[3] += fp8dec(v.x >> 24);    \
            ACC[4] += fp8dec(v.y & 255); ACC[5] += fp8dec((v.y >> 8) & 255);     \
            ACC[6] += fp8dec((v.y >> 16) & 255); ACC[7] += fp8dec(v.y >> 24);    \
        } else {                                                                 \
            short8 v = ld8((const unsigned short*)(table + 2 * (size_t)(O)) + sl * 8); \
            for (int k = 0; k < 8; ++k)                                          \
                ACC[k] += bf2f(((const unsigned short*)&v)[k]);                  \
        }                                                                        \
    }
    for (; jj + 16 <= j1; jj += 16) {
        unsigned o0 = bucket2[jj + oct];
        unsigned o1 = bucket2[jj + 8 + oct];
        GATHER8(o0, acc)
        GATHER8(o1, acc2)
    }
    if (jj + 8 <= j1) {
        unsigned o = bucket2[jj + oct];
        GATHER8(o, acc)
        jj += 8;
    }
    if (oct < j1 - jj) {
        unsigned o = bucket2[jj + oct];
        GATHER8(o, acc2)
    }
#undef GATHER8
#pragma unroll
    for (int k = 0; k < 8; ++k) {
        acc[k] += acc2[k];
        acc[k] += __shfl_xor(acc[k], 8);
        acc[k] += __shfl_xor(acc[k], 16);
        acc[k] += __shfl_xor(acc[k], 32);
    }
    if (oct == 0) {
        size_t baseo = (size_t)(NSLOT - 1) * SSTR + (size_t)e * HID;
        float bse[8];
        if (FP8) {
            uint2 v = *(const uint2*)(table + baseo + sl * 8);
            bse[0] = fp8dec(v.x & 255); bse[1] = fp8dec((v.x >> 8) & 255);
            bse[2] = fp8dec((v.x >> 16) & 255); bse[3] = fp8dec(v.x >> 24);
            bse[4] = fp8dec(v.y & 255); bse[5] = fp8dec((v.y >> 8) & 255);
            bse[6] = fp8dec((v.y >> 16) & 255); bse[7] = fp8dec(v.y >> 24);
        } else {
            short8 v = ld8((const unsigned short*)(table + 2 * baseo) + sl * 8);
#pragma unroll
            for (int k = 0; k < 8; ++k) bse[k] = bf2f(((const unsigned short*)&v)[k]);
        }
        float v[8];
#pragma unroll
        for (int k = 0; k < 8; ++k) {
            float x = acc[k] + bse[k];
            v[k] = (x >= 0.f) ? x : 0.01f * x;
        }
        if (writeBf) {
            unsigned short pk[8];
#pragma unroll
            for (int k = 0; k < 8; ++k) pk[k] = f2bf(v[k]);
            *(short8*)&Abf[(size_t)e * HID + sl * 8] = *(const short8*)pk;
        } else {
            *(float4*)&outF[(size_t)e * HID + sl * 8] = make_float4(v[0], v[1], v[2], v[3]);
            *(float4*)&outF[(size_t)e * HID + sl * 8 + 4] = make_float4(v[4], v[5], v[6], v[7]);
        }
    }
}

// ============================================================
// fallback path (round-1 atomic kernels) — used only if ws too small
// ============================================================

__global__ void k_rel(const float* __restrict__ Wpr0, const float* __restrict__ Wmr1,
                      const float* __restrict__ Wpr1, float* __restrict__ diag1,
                      float* __restrict__ outrel) {
    __shared__ float wp[HID];
    int rr = blockIdx.x, d = threadIdx.x;
    wp[d] = Wpr0[d * NUM_REL + rr];
    __syncthreads();
    float s1 = 0.0f, s2 = 0.0f;
    const float* wmr = Wmr1 + (size_t)(rr * HID + d) * HID;
    const float* wpr = Wpr1 + d * HID;
    for (int k = 0; k < HID; k++) { s1 += wp[k] * wmr[k]; s2 += wp[k] * wpr[k]; }
    diag1[rr * HID + d] = s1;
    outrel[rr * HID + d] = s2;
}

__global__ void k_init_u0(const float* __restrict__ Wres0, float* __restrict__ U0) {
    __shared__ float tile[64][65];
    int e0 = blockIdx.x * 64;
    for (int i = threadIdx.x; i < 64 * 64; i += 256) {
        int dd = i >> 6, xx = i & 63;
        if (e0 + xx < NUM_ENT) tile[xx][dd] = Wres0[dd * NUM_ENT + e0 + xx];
    }
    __syncthreads();
    for (int i = threadIdx.x; i < 64 * 64; i += 256) {
        int ee = i >> 6, dd = i & 63;
        if (e0 + ee < NUM_ENT) U0[(e0 + ee) * HID + dd] = tile[ee][dd];
    }
}

__global__ void k_hist(const int* __restrict__ r, int* __restrict__ hist) {
    __shared__ int lh[NUM_REL];
    int tid = threadIdx.x;
    if (tid < NUM_REL) lh[tid] = 0;
    __syncthreads();
    int i = blockIdx.x * blockDim.x + tid;
    if (i < NTRIP) atomicAdd(&lh[r[i]], 1);
    __syncthreads();
    if (tid < NUM_REL && lh[tid] > 0) atomicAdd(&hist[tid], lh[tid]);
}

__global__ void k_scan_small(const int* __restrict__ hist, int* __restrict__ off,
                             int* __restrict__ cur) {
    if (threadIdx.x == 0 && blockIdx.x == 0) {
        int s = 0;
        for (int i = 0; i < NUM_REL; i++) { off[i] = s; cur[i] = s; s += hist[i]; }
        off[NUM_REL] = s;
    }
}

__global__ void k_bucket(const int* __restrict__ h, const int* __restrict__ r,
                         const int* __restrict__ t, int* __restrict__ cur,
                         int2* __restrict__ bucket) {
    __shared__ int lcnt[NUM_REL];
    __shared__ int lbase[NUM_REL];
    int tid = threadIdx.x;
    if (tid < NUM_REL) lcnt[tid] = 0;
    __syncthreads();
    int i = blockIdx.x * blockDim.x + tid;
    int rr = -1, lpos = 0;
    if (i < NTRIP) { rr = r[i]; lpos = atomicAdd(&lcnt[rr], 1); }
    __syncthreads();
    if (tid < NUM_REL && lcnt[tid] > 0) lbase[tid] = atomicAdd(&cur[tid], lcnt[tid]);
    __syncthreads();
    if (i < NTRIP) bucket[lbase[rr] + lpos] = make_int2(h[i], t[i]);
}

__global__ void k_l0(const float* __restrict__ Wme0, const float* __restrict__ Wmr0,
                     const int* __restrict__ off, const int2* __restrict__ bucket,
                     float* __restrict__ U0) {
    __shared__ float row[NUM_ENT];
    int rr = blockIdx.x >> 6;
    int d  = blockIdx.x & 63;
    const float4* src4 = (const float4*)(Wme0 + (size_t)(rr * HID + d) * NUM_ENT);
    float4* row4 = (float4*)row;
    for (int i = threadIdx.x; i < NUM_ENT / 4; i += blockDim.x) row4[i] = src4[i];
    __syncthreads();
    float wd0 = Wmr0[(size_t)(rr * HID + d) * NUM_REL + rr];
    int b0 = off[rr], b1 = off[rr + 1];
    for (int i = b0 + threadIdx.x; i < b1; i += blockDim.x) {
        int2 ht = bucket[i];
        atomicAdd(&U0[(size_t)ht.y * HID + d], row[ht.x] + wd0);
    }
}

__global__ void k_lrelu(float* __restrict__ x, int n) {
    int i = blockIdx.x * blockDim.x + threadIdx.x;
    if (i < n) { float v = x[i]; x[i] = v >= 0.0f ? v : 0.01f * v; }
}

__global__ void k_init_u1(const float* __restrict__ A, const float* __restrict__ Wres1,
                          float* __restrict__ out) {
    __shared__ float W[HID][HID + 1];
    int tid = threadIdx.x;
    for (int i = tid; i < HID * HID; i += 256) W[i >> 6][i & 63] = Wres1[i];
    __syncthreads();
    int g = blockIdx.x * 256 + tid;
    int e = g >> 6, d = g & 63;
    if (e >= NUM_ENT) return;
    const float4* arow = (const float4*)(A + (size_t)e * HID);
    float acc = 0.0f;
#pragma unroll
    for (int k4 = 0; k4 < 16; k4++) {
        float4 a = arow[k4];
        acc = fmaf(a.x, W[d][k4 * 4 + 0], acc);
        acc = fmaf(a.y, W[d][k4 * 4 + 1], acc);
        acc = fmaf(a.z, W[d][k4 * 4 + 2], acc);
        acc = fmaf(a.w, W[d][k4 * 4 + 3], acc);
    }
    out[g] = acc;
}

#define L1_CHUNKS 16
__global__ void k_l1(const float* __restrict__ A, const float* __restrict__ Wme1,
                     const int* __restrict__ off, const int2* __restrict__ bucket,
                     const float* __restrict__ diag1, float* __restrict__ out) {
    int rr = blockIdx.x / L1_CHUNKS;
    int chunk = blockIdx.x % L1_CHUNKS;
    int b0 = off[rr], b1 = off[rr + 1];
    for (int i = b0 + chunk * 256 + (int)threadIdx.x; i < b1; i += L1_CHUNKS * 256) {
        int2 ht = bucket[i];
        const float4* arow = (const float4*)(A + (size_t)ht.x * HID);
        float4 a[16];
#pragma unroll
        for (int j = 0; j < 16; j++) a[j] = arow[j];
        float* op = out + (size_t)ht.y * HID;
#pragma unroll 4
        for (int d = 0; d < HID; d++) {
            const float4* m4 = (const float4*)(Wme1 + (size_t)(rr * HID + d) * HID);
            float acc = diag1[rr * HID + d];
#pragma unroll
            for (int k = 0; k < 16; k++) {
                float4 m = m4[k];
                acc = fmaf(a[k].x, m.x, acc);
                acc = fmaf(a[k].y, m.y, acc);
                acc = fmaf(a[k].z, m.z, acc);
                acc = fmaf(a[k].w, m.w, acc);
            }
            atomicAdd(op + d, acc);
        }
    }
}

// ============================================================
// launch
// ============================================================

static inline size_t align_up(size_t x, size_t a) { return (x + a - 1) & ~(a - 1); }

extern "C" void kernel_launch(void* const* d_in, const int* in_sizes, int n_in,
                              void* d_out, int out_size, void* d_ws, size_t ws_size,
                              hipStream_t stream) {
    const float* Wres0 = (const float*)d_in[0];
    const float* Wme0  = (const float*)d_in[1];
    const float* Wmr0  = (const float*)d_in[2];
    const float* Wpr0  = (const float*)d_in[3];
    const float* Wres1 = (const float*)d_in[4];
    const float* Wme1  = (const float*)d_in[5];
    const float* Wmr1  = (const float*)d_in[6];
    const float* Wpr1  = (const float*)d_in[7];
    const int* h = (const int*)d_in[8];
    const int* r = (const int*)d_in[9];
    const int* t = (const int*)d_in[10];
    float* out = (float*)d_out;  // [640000 ent | 3200 rel]

    char* ws = (char*)d_ws;
    const int nbt = (NTRIP + 255) / 256;       // 1954

    // workspace layout (fast path); Tab shared: fp8 P then bf16 B
    size_t p = 0;
    size_t oTab  = p; p += align_up((size_t)NSLOT * SSTR * 2, 256);   // 65.28 MB
    size_t oB2   = p; p += align_up((size_t)NUM_ENT * BSTR * 4, 256); // 7.68 MB
    size_t oBins = p; p += align_up((size_t)NUM_ENT * 4, 256);
    size_t oAbf  = p; p += align_up((size_t)NUM_ENT * HID * 2, 256);
    size_t oD0   = p; p += align_up((size_t)NSLOT * HID * 4, 256);
    size_t oD1   = p; p += align_up((size_t)NSLOT * HID * 4, 256);
    size_t oWb   = p; p += align_up((size_t)NSLOT * HID * HID * 2, 256);
    size_t need = p;

    if (need <= ws_size) {
        unsigned char*  Tab8 = (unsigned char*)(ws + oTab);   // P (fp8) then B (bf16)
        unsigned short* TabH = (unsigned short*)(ws + oTab);
        unsigned* bucket2   = (unsigned*)(ws + oB2);
        int*      bins      = (int*)(ws + oBins);
        unsigned short* Abf = (unsigned short*)(ws + oAbf);
        float*    diag0     = (float*)(ws + oD0);
        float*    diag1     = (float*)(ws + oD1);
        unsigned short* Wb  = (unsigned short*)(ws + oWb);
        const int netile256 = (NUM_ENT + 255) / 256;          // 40
        const int nsplit = 13;
        const int percut = (NSLOT + nsplit - 1) / nsplit;     // 4

        // 1. fused prep (zero bins | diag0 | rel | Wb | diag1-tail)
        k_prep<<<883, 256, 0, stream>>>(Wmr0, Wpr0, Wmr1, Wpr1, Wme1, Wres1,
                                        bins, diag0, diag1, out + NUM_ENT * HID, Wb);
        // 2. fused transpose -> fp8 P + one-pass rank&fill
        k_build<<<TRB + nbt, 256, 0, stream>>>(Wme0, Wres0, diag0, Tab8,
                                               h, r, t, bins, bucket2);
        // 3. layer-0 gather (fp8) -> Abf (bf16 A)
        k_scatter<1><<<(NUM_ENT + 3) / 4, 256, 0, stream>>>(
            Tab8, bins, bucket2, Abf, out, 1);
        // 4. layer-1 table (MFMA, 256-row tiles) -> bf16 B (overwrites P)
        k_gemmB<<<dim3(netile256, nsplit), 256, 0, stream>>>(Abf, Wb, diag1, TabH,
                                                             percut);
        // 5. layer-1 gather (bf16) -> out
        k_scatter<0><<<(NUM_ENT + 3) / 4, 256, 0, stream>>>(
            Tab8, bins, bucket2, Abf, out, 0);
        return;
    }

    // ---------- fallback: round-1 atomic path ----------
    {
        const int net = (NUM_ENT + 63) / 64;
        int2*  bucket = (int2*)ws;                    // 4,000,000 B
        float* U0     = (float*)(ws + 4000000);       // 2,560,000 B
        float* diag1  = (float*)(ws + 6560000);       // 12,800 B
        int*   hist   = (int*)(ws + 6572800);
        int*   off    = (int*)(ws + 6573056);
        int*   cur    = (int*)(ws + 6573312);

        hipMemsetAsync(hist, 0, NUM_REL * sizeof(int), stream);
        k_hist<<<nbt, 256, 0, stream>>>(r, hist);
        k_scan_small<<<1, 64, 0, stream>>>(hist, off, cur);
        k_bucket<<<nbt, 256, 0, stream>>>(h, r, t, cur, bucket);

        k_init_u0<<<net, 256, 0, stream>>>(Wres0, U0);
        k_l0<<<NUM_REL * HID, 256, 0, stream>>>(Wme0, Wmr0, off, bucket, U0);
        k_lrelu<<<(NUM_ENT * HID + 255) / 256, 256, 0, stream>>>(U0, NUM_ENT * HID);

        k_rel<<<NUM_REL, HID, 0, stream>>>(Wpr0, Wmr1, Wpr1, diag1, out + NUM_ENT * HID);
        k_init_u1<<<(NUM_ENT * HID) / 256, 256, 0, stream>>>(U0, Wres1, out);
        k_l1<<<NUM_REL * L1_CHUNKS, 256, 0, stream>>>(U0, Wme1, off, bucket, diag1, out);
        k_lrelu<<<(NUM_ENT * HID + 255) / 256, 256, 0, stream>>>(out, NUM_ENT * HID);
    }
}